// Round 10
// baseline (198.991 us; speedup 1.0000x reference)
//
#include <hip/hip_runtime.h>

#define NA 16
#define DD 513
#define ALPHA 0.1f
#define EPSV 1e-7f
#define GRID 8192   // 8192 blocks * 16 rows = 131072

typedef __fp16 h2v __attribute__((ext_vector_type(2)));
typedef __fp16 f16x8 __attribute__((ext_vector_type(8)));
typedef float f32x4 __attribute__((ext_vector_type(4)));
typedef unsigned int u32;

union H2U { h2v h; u32 u; };
union FU  { float f; u32 u; int i; };
union FRAG { u32 w[4]; f16x8 v; };
union U4   { uint4 v; u32 w[4]; };

static __device__ __forceinline__ u32 pkrtz(float lo, float hi) {
    H2U t; t.h = __builtin_amdgcn_cvt_pkrtz(lo, hi); return t.u;
}
static __device__ __forceinline__ h2v asH2(u32 w) { H2U t; t.u = w; return t.h; }

// Frame layout (R8-verified): granule G = kt*64 + l holds 4 f16-pairs of
// source-row (l&15), k-slot lp = 4*kt + (l>>4); pair q = (lp+128q, lp+64+128q).
// XOR-swizzle keeps stage-write / mfma-read / store-read / y-gather bank-clean.
static __device__ __forceinline__ int swz(int G) {
    return G ^ (((G >> 4) & 3) | (((G >> 6) & 1) << 2));
}

__global__ __launch_bounds__(256, 5)
void hfield_kernel(const float* __restrict__ x,
                   const float* __restrict__ anc,
                   float* __restrict__ out) {
    __shared__ uint4 bframe[1024];        // anchors, 16 KB (block-wide)
    __shared__ uint4 xframe[1024];        // x tile,  16 KB (block-wide)

    const int tid = threadIdx.x, lane = tid & 63, wid = tid >> 6;
    const int col = lane & 15, g = lane >> 4;

    // ---- stage anchors into bframe (whole block) ----
#pragma unroll
    for (int m = 0; m < 4; ++m) {
        const int F = m * 256 + tid;
        const int l = F & 63, kt = F >> 6;
        const int a = l & 15, lp = 4 * kt + (l >> 4);
        const float* p = anc + a * DD + 1 + lp;
        uint4 w;
        w.x = pkrtz(p[0],   p[64]);
        w.y = pkrtz(p[128], p[192]);
        w.z = pkrtz(p[256], p[320]);
        w.w = pkrtz(p[384], p[448]);
        bframe[swz(F)] = w;
    }

    // ---- af0 for anchor `col` (per-wave, exact f32) ----
    float af0c;
    {
        const float* p = anc + col * DD + 1 + g * 128;
        float s = 0.f;
#pragma unroll 16
        for (int i = 0; i < 128; ++i) s = fmaf(p[i], p[i], s);
        s += __shfl_xor(s, 16);
        s += __shfl_xor(s, 32);
        af0c = sqrtf(1.0f + s);
    }

    const int rowbase = blockIdx.x * 16;
    const float* xb = x + (size_t)rowbase * DD;

    // x0 for the 4 rows this lane-group owns (C-layout row = 4g + r4)
    float x0r[4];
#pragma unroll
    for (int r4 = 0; r4 < 4; ++r4) x0r[r4] = xb[(size_t)(4 * g + r4) * DD];

    // ---- stage x tile cooperatively: wave `wid` stages rows 4*wid..4*wid+3 ----
#pragma unroll
    for (int rr = 0; rr < 4; ++rr) {
        const int r = 4 * wid + rr;
        const float* p = xb + (size_t)r * DD + 1 + lane;
        float v[8];
#pragma unroll
        for (int j = 0; j < 8; ++j) v[j] = p[64 * j];
        uint4 w;
        w.x = pkrtz(v[0], v[1]);
        w.y = pkrtz(v[2], v[3]);
        w.z = pkrtz(v[4], v[5]);
        w.w = pkrtz(v[6], v[7]);
        xframe[swz((lane >> 2) * 64 + 16 * (lane & 3) + r)] = w;
    }
    __syncthreads();

    // ---- MFMA: S[row][anchor], 16 rows x 16 anchors, K=512 ----
    // All 4 waves compute the full tile redundantly (MFMA util is ~0.5%, free;
    // buys: no split-K reduce, no second barrier, no 64-reg store array).
    f32x4 acc = {0.f, 0.f, 0.f, 0.f};
#pragma unroll
    for (int kt = 0; kt < 16; ++kt) {
        FRAG A, B;
        U4 ax, bx;
        ax.v = xframe[swz(kt * 64 + lane)];
        bx.v = bframe[swz(kt * 64 + lane)];
        A.w[0] = ax.w[0]; A.w[1] = ax.w[1]; A.w[2] = ax.w[2]; A.w[3] = ax.w[3];
        B.w[0] = bx.w[0]; B.w[1] = bx.w[1]; B.w[2] = bx.w[2]; B.w[3] = bx.w[3];
        acc = __builtin_amdgcn_mfma_f32_16x16x32_f16(A.v, B.v, acc, 0, 0, 0);
    }

    // ---- theta, argmin, epilogue: 4 independent chains per lane ----
    const float thmin = 1.0f + 1e-7f;
    float c1r[4], c2r[4], o0r[4];
    int bir[4];
#pragma unroll
    for (int r4 = 0; r4 < 4; ++r4) {
        const float th = fmaxf(fmaf(x0r[r4], af0c, -acc[r4]), thmin);
        FU u; u.f = th;
        u32 key = (u.u & 0xFFFFFFF0u) | (u32)col;
#pragma unroll
        for (int m = 1; m <= 8; m <<= 1) {
            const u32 o = (u32)__shfl_xor((int)key, m);
            key = o < key ? o : key;
        }
        const int bi  = (int)(key & 15u);
        const int src = (lane & 48) | bi;
        const float thw = __shfl(th, src);     // exact winner theta
        const float y0  = __shfl(af0c, src);   // winner af0

        const float s2 = thw * thw - 1.0f;
        const float rr = sqrtf(s2);
        const float ac = __logf(thw + rr);     // arccosh
        const float cf = ac / rr;
        const float vn = sqrtf(fmaxf(ALPHA * ALPHA * ac * ac, EPSV));
        const float e  = __expf(vn);
        const float ei = 1.0f / e;
        const float ch = 0.5f * (e + ei);
        const float sh = 0.5f * (e - ei);
        const float c2 = ALPHA * cf * (sh / vn);
        const float c1 = fmaf(-c2, thw, ch);

        c1r[r4] = c1;
        c2r[r4] = c2;
        o0r[r4] = fmaf(c2, y0, c1 * x0r[r4]);
        bir[r4] = bi;
    }

    // ---- store phase: wave `wid` stores rows 4*wid..4*wid+3 ----
    // Coefficients for row 4*wid + rr live (uniformly) in lane-group g == wid.
#pragma unroll
    for (int rr = 0; rr < 4; ++rr) {
        const int r   = 4 * wid + rr;
        const int src = 16 * wid;
        const float c1 = __shfl(c1r[rr], src);
        const float c2 = __shfl(c2r[rr], src);
        const float o0 = __shfl(o0r[rr], src);
        const int   bi = __builtin_amdgcn_readfirstlane(__shfl(bir[rr], src));

        U4 X, Y;
        X.v = xframe[swz((lane >> 2) * 64 + 16 * (lane & 3) + r)];
        Y.v = bframe[swz((lane >> 2) * 64 + 16 * (lane & 3) + bi)];

        float* op = out + (size_t)(rowbase + r) * DD;
        if (lane == 0) __builtin_nontemporal_store(o0, op);
#pragma unroll
        for (int q = 0; q < 4; ++q) {
            const h2v hx = asH2(X.w[q]);
            const h2v hy = asH2(Y.w[q]);
            __builtin_nontemporal_store(fmaf(c2, (float)hy.x, c1 * (float)hx.x),
                                        &op[1 + lane + 128 * q]);
            __builtin_nontemporal_store(fmaf(c2, (float)hy.y, c1 * (float)hx.y),
                                        &op[1 + lane + 64 + 128 * q]);
        }
    }
}

extern "C" void kernel_launch(void* const* d_in, const int* in_sizes, int n_in,
                              void* d_out, int out_size, void* d_ws, size_t ws_size,
                              hipStream_t stream) {
    const float* x   = (const float*)d_in[0];
    const float* anc = (const float*)d_in[1];
    float* out       = (float*)d_out;
    hipLaunchKernelGGL(hfield_kernel, dim3(GRID), dim3(256), 0, stream, x, anc, out);
}

// Round 11
// 111.099 us; speedup vs baseline: 1.7911x; 1.7911x over previous
//
#include <hip/hip_runtime.h>

#define NA 16
#define DD 513
#define ALPHA 0.1f
#define EPSV 1e-7f
#define TPW 2
#define GRID 1024   // 1024 blocks * 4 waves * 2 tiles * 16 rows = 131072

typedef __fp16 h2v __attribute__((ext_vector_type(2)));
typedef __fp16 f16x8 __attribute__((ext_vector_type(8)));
typedef float f32x4 __attribute__((ext_vector_type(4)));
typedef unsigned int u32;

union H2U { h2v h; u32 u; };
union FU  { float f; u32 u; int i; };
union FRAG { u32 w[4]; f16x8 v; };
union U4   { uint4 v; u32 w[4]; };

static __device__ __forceinline__ u32 pkrtz(float lo, float hi) {
    H2U t; t.h = __builtin_amdgcn_cvt_pkrtz(lo, hi); return t.u;
}
static __device__ __forceinline__ h2v asH2(u32 w) { H2U t; t.u = w; return t.h; }

// Frame layout (R8-verified): granule G = kt*64 + l holds 4 f16-pairs of
// source-row (l&15), k-slot lp = 4*kt + (l>>4); pair q = (lp+128q, lp+64+128q).
// XOR-swizzle keeps stage-write / mfma-read / store-read / y-gather bank-clean.
static __device__ __forceinline__ int swz(int G) {
    return G ^ (((G >> 4) & 3) | (((G >> 6) & 1) << 2));
}

__global__ __launch_bounds__(256, 2)
void hfield_kernel(const float* __restrict__ x,
                   const float* __restrict__ anc,
                   float* __restrict__ out) {
    __shared__ uint4 bframe[1024];        // anchors, 16 KB (block-wide)
    __shared__ uint4 xframe[4][1024];     // x tile, 16 KB per wave

    const int tid = threadIdx.x, lane = tid & 63, wid = tid >> 6;
    const int col = lane & 15, g = lane >> 4;

    const int rowbase0 = (blockIdx.x * 4 + wid) * (16 * TPW);
    const float* xb = x + (size_t)rowbase0 * DD;
    uint4* xf = xframe[wid];

    // ---- issue tile-0 load burst FIRST (HBM latency hides under prologue) ----
    float nv[16][8];
#pragma unroll
    for (int r = 0; r < 16; ++r) {
        const float* p = xb + (size_t)r * DD + 1 + lane;
#pragma unroll
        for (int j = 0; j < 8; ++j) nv[r][j] = p[64 * j];
    }
    // x0 for all tiles (lane-group g owns rows 4g..4g+3 of each tile)
    float x0r[TPW][4];
#pragma unroll
    for (int t = 0; t < TPW; ++t)
#pragma unroll
        for (int r4 = 0; r4 < 4; ++r4)
            x0r[t][r4] = xb[(size_t)(t * 16 + 4 * g + r4) * DD];
    __builtin_amdgcn_sched_barrier(0);

    // ---- stage anchors into bframe ----
#pragma unroll
    for (int m = 0; m < 4; ++m) {
        const int F = m * 256 + tid;
        const int l = F & 63, kt = F >> 6;
        const int a = l & 15, lp = 4 * kt + (l >> 4);
        const float* p = anc + a * DD + 1 + lp;
        uint4 w;
        w.x = pkrtz(p[0],   p[64]);
        w.y = pkrtz(p[128], p[192]);
        w.z = pkrtz(p[256], p[320]);
        w.w = pkrtz(p[384], p[448]);
        bframe[swz(F)] = w;
    }

    // ---- af0 for anchor `col` (exact f32) ----
    float af0c;
    {
        const float* p = anc + col * DD + 1 + g * 128;
        float s = 0.f;
#pragma unroll 16
        for (int i = 0; i < 128; ++i) s = fmaf(p[i], p[i], s);
        s += __shfl_xor(s, 16);
        s += __shfl_xor(s, 32);
        af0c = sqrtf(1.0f + s);
    }
    __syncthreads();

    const float thmin = 1.0f + 1e-7f;

#pragma unroll
    for (int t = 0; t < TPW; ++t) {
        const int rowbase = rowbase0 + t * 16;

        // ---- drain regs -> xframe (waits on this tile's loads) ----
        if (t > 0)  // store-phase reads of previous tile must complete first
            asm volatile("s_waitcnt lgkmcnt(0)" ::: "memory");
#pragma unroll
        for (int r = 0; r < 16; ++r) {
            uint4 w;
            w.x = pkrtz(nv[r][0], nv[r][1]);
            w.y = pkrtz(nv[r][2], nv[r][3]);
            w.z = pkrtz(nv[r][4], nv[r][5]);
            w.w = pkrtz(nv[r][6], nv[r][7]);
            xf[swz((lane >> 2) * 64 + 16 * (lane & 3) + r)] = w;
        }

        // ---- regs free: issue NEXT tile's load burst (hides under MFMA+store) ----
        if (t + 1 < TPW) {
            const float* nb = xb + (size_t)((t + 1) * 16) * DD;
#pragma unroll
            for (int r = 0; r < 16; ++r) {
                const float* p = nb + (size_t)r * DD + 1 + lane;
#pragma unroll
                for (int j = 0; j < 8; ++j) nv[r][j] = p[64 * j];
            }
            __builtin_amdgcn_sched_barrier(0);
        }

        asm volatile("s_waitcnt lgkmcnt(0)" ::: "memory");

        // ---- MFMA: S[row][anchor], 16 rows x 16 anchors, K=512 ----
        f32x4 acc = {0.f, 0.f, 0.f, 0.f};
#pragma unroll
        for (int kt = 0; kt < 16; ++kt) {
            FRAG A, B;
            U4 ax, bx;
            ax.v = xf[swz(kt * 64 + lane)];
            bx.v = bframe[swz(kt * 64 + lane)];
            A.w[0] = ax.w[0]; A.w[1] = ax.w[1]; A.w[2] = ax.w[2]; A.w[3] = ax.w[3];
            B.w[0] = bx.w[0]; B.w[1] = bx.w[1]; B.w[2] = bx.w[2]; B.w[3] = bx.w[3];
            acc = __builtin_amdgcn_mfma_f32_16x16x32_f16(A.v, B.v, acc, 0, 0, 0);
        }

        // ---- theta, argmin, epilogue: 4 independent chains per lane ----
        float c1r[4], c2r[4], o0r[4];
        int bir[4];
#pragma unroll
        for (int r4 = 0; r4 < 4; ++r4) {
            const float th = fmaxf(fmaf(x0r[t][r4], af0c, -acc[r4]), thmin);
            FU u; u.f = th;
            u32 key = (u.u & 0xFFFFFFF0u) | (u32)col;
#pragma unroll
            for (int m = 1; m <= 8; m <<= 1) {
                const u32 o = (u32)__shfl_xor((int)key, m);
                key = o < key ? o : key;
            }
            const int bi  = (int)(key & 15u);
            const int src = (lane & 48) | bi;
            const float thw = __shfl(th, src);     // exact winner theta
            const float y0  = __shfl(af0c, src);   // winner af0

            const float s2 = thw * thw - 1.0f;
            const float rr = sqrtf(s2);
            const float ac = __logf(thw + rr);     // arccosh
            const float cf = ac / rr;
            const float vn = sqrtf(fmaxf(ALPHA * ALPHA * ac * ac, EPSV));
            const float e  = __expf(vn);
            const float ei = 1.0f / e;
            const float ch = 0.5f * (e + ei);
            const float sh = 0.5f * (e - ei);
            const float c2 = ALPHA * cf * (sh / vn);
            const float c1 = fmaf(-c2, thw, ch);

            c1r[r4] = c1;
            c2r[r4] = c2;
            o0r[r4] = fmaf(c2, y0, c1 * x0r[t][r4]);
            bir[r4] = bi;
        }

        // ---- store phase: 16 rows, sequential contiguous nt streams ----
#pragma unroll 4
        for (int r = 0; r < 16; ++r) {
            const int src = (r >> 2) * 16;                   // producer group
            const float c1 = __shfl(c1r[r & 3], src);
            const float c2 = __shfl(c2r[r & 3], src);
            const float o0 = __shfl(o0r[r & 3], src);
            const int   bi = __builtin_amdgcn_readfirstlane(__shfl(bir[r & 3], src));

            U4 X, Y;
            X.v = xf[swz((lane >> 2) * 64 + 16 * (lane & 3) + r)];
            Y.v = bframe[swz((lane >> 2) * 64 + 16 * (lane & 3) + bi)];

            float* op = out + (size_t)(rowbase + r) * DD;
            if (lane == 0) __builtin_nontemporal_store(o0, op);
#pragma unroll
            for (int q = 0; q < 4; ++q) {
                const h2v hx = asH2(X.w[q]);
                const h2v hy = asH2(Y.w[q]);
                __builtin_nontemporal_store(fmaf(c2, (float)hy.x, c1 * (float)hx.x),
                                            &op[1 + lane + 128 * q]);
                __builtin_nontemporal_store(fmaf(c2, (float)hy.y, c1 * (float)hx.y),
                                            &op[1 + lane + 64 + 128 * q]);
            }
        }
    }
}

extern "C" void kernel_launch(void* const* d_in, const int* in_sizes, int n_in,
                              void* d_out, int out_size, void* d_ws, size_t ws_size,
                              hipStream_t stream) {
    const float* x   = (const float*)d_in[0];
    const float* anc = (const float*)d_in[1];
    float* out       = (float*)d_out;
    hipLaunchKernelGGL(hfield_kernel, dim3(GRID), dim3(256), 0, stream, x, anc, out);
}

// Round 13
// 103.877 us; speedup vs baseline: 1.9156x; 1.0695x over previous
//
#include <hip/hip_runtime.h>

#define NA 16
#define DD 513
#define ALPHA 0.1f
#define EPSV 1e-7f
#define TPW 4
#define GRID 1024   // 1024 blocks * 4 waves * 4 tiles * 8 rows = 131072

typedef __fp16 h2v __attribute__((ext_vector_type(2)));
typedef __fp16 f16x8 __attribute__((ext_vector_type(8)));
typedef float f32x4 __attribute__((ext_vector_type(4)));
typedef float f32x4u __attribute__((ext_vector_type(4), aligned(4)));  // 4B-aligned vec4
typedef unsigned int u32;

union H2U { h2v h; u32 u; };
union FU  { float f; u32 u; int i; };
union FRAG { u32 w[4]; f16x8 v; };
union U4   { uint4 v; u32 w[4]; };

static __device__ __forceinline__ u32 pkrtz(float lo, float hi) {
    H2U t; t.h = __builtin_amdgcn_cvt_pkrtz(lo, hi); return t.u;
}
static __device__ __forceinline__ h2v asH2(u32 w) { H2U t; t.u = w; return t.h; }

// 4-byte-aligned 16B vector (rows are only 4B aligned)
struct __attribute__((packed, aligned(4))) F4 { float x, y, z, w; };

// Frame: row-frame = 64 uint4 chunks. Chunk u of a row holds f16 of elements
// (spatial idx) {4u..4u+3} and {256+4u..256+4u+3}:  w = {pk(4u,4u+1),
// pk(4u+2,4u+3), pk(256+4u,256+4u+1), pk(256+4u+2,256+4u+3)}.
// Stored at frame[row][u ^ (row&7)] -- involution swizzle; conflict-free for
// stage-write (u=lane), MFMA read (u=4kt+g across 16 cols), store-read and
// y-gather (u=lane, single row). A and B frames use the SAME enumeration, so
// the MFMA dot over k is a consistent permutation (R7/R8-verified invariant).

__global__ __launch_bounds__(256, 3)
void hfield_kernel(const float* __restrict__ x,
                   const float* __restrict__ anc,
                   float* __restrict__ out) {
    __shared__ uint4 bframe[NA * 64];       // anchors, 16 KB (block-wide)
    __shared__ uint4 xframe[4][8 * 64];     // x tile, 8 KB per wave

    const int tid = threadIdx.x, lane = tid & 63, wid = tid >> 6;
    const int col = lane & 15, g = lane >> 4;

    const int rowbase0 = (blockIdx.x * 4 + wid) * (8 * TPW);
    const float* xb = x + (size_t)rowbase0 * DD;
    uint4* xf = xframe[wid];

    // ---- issue tile-0 load burst FIRST: 16 dwordx4, 64 VGPRs in flight ----
    F4 nvA[8], nvB[8];
#pragma unroll
    for (int r = 0; r < 8; ++r) {
        const float* p = xb + (size_t)r * DD + 1 + 4 * lane;
        nvA[r] = *(const F4*)p;
        nvB[r] = *(const F4*)(p + 256);
    }
    __builtin_amdgcn_sched_barrier(0);

    // ---- stage anchors into bframe ----
#pragma unroll
    for (int m = 0; m < 4; ++m) {
        const int i = m * 256 + tid;            // 0..1023
        const int a = i >> 6, u = i & 63;
        const float* p = anc + a * DD + 1 + 4 * u;
        const float* q = p + 256;
        uint4 w;
        w.x = pkrtz(p[0], p[1]);
        w.y = pkrtz(p[2], p[3]);
        w.z = pkrtz(q[0], q[1]);
        w.w = pkrtz(q[2], q[3]);
        bframe[a * 64 + (u ^ (a & 7))] = w;
    }

    // ---- af0 for anchor `col` (exact f32) ----
    float af0c;
    {
        const float* p = anc + col * DD + 1 + g * 128;
        float s = 0.f;
#pragma unroll 16
        for (int i = 0; i < 128; ++i) s = fmaf(p[i], p[i], s);
        s += __shfl_xor(s, 16);
        s += __shfl_xor(s, 32);
        af0c = sqrtf(1.0f + s);
    }
    __syncthreads();

    const float thmin = 1.0f + 1e-7f;

#pragma unroll 1
    for (int t = 0; t < TPW; ++t) {
        const int rowbase = rowbase0 + t * 8;

        // ---- drain regs -> xframe (f16 chunks, swizzled) ----
#pragma unroll
        for (int r = 0; r < 8; ++r) {
            uint4 w;
            w.x = pkrtz(nvA[r].x, nvA[r].y);
            w.y = pkrtz(nvA[r].z, nvA[r].w);
            w.z = pkrtz(nvB[r].x, nvB[r].y);
            w.w = pkrtz(nvB[r].z, nvB[r].w);
            xf[r * 64 + (lane ^ (r & 7))] = w;
        }

        // ---- regs free: issue NEXT tile's burst (hides under MFMA+store) ----
        if (t + 1 < TPW) {
            const float* nb = xb + (size_t)((t + 1) * 8) * DD;
#pragma unroll
            for (int r = 0; r < 8; ++r) {
                const float* p = nb + (size_t)r * DD + 1 + 4 * lane;
                nvA[r] = *(const F4*)p;
                nvB[r] = *(const F4*)(p + 256);
            }
            __builtin_amdgcn_sched_barrier(0);
        }

        // x0 for this lane-group's rows (rows 8..15 duplicate 0..7; L1-hot)
        float x0r[4];
#pragma unroll
        for (int r4 = 0; r4 < 4; ++r4)
            x0r[r4] = xb[(size_t)(t * 8 + ((4 * g + r4) & 7)) * DD];

        // ---- MFMA: S[row][anchor], 8 real rows (x2 dup) x 16 anchors, K=512 ----
        f32x4 acc = {0.f, 0.f, 0.f, 0.f};
#pragma unroll
        for (int kt = 0; kt < 16; ++kt) {
            const int u = 4 * kt + g;
            FRAG A, B;
            U4 ax, bx;
            ax.v = xf[(col & 7) * 64 + (u ^ (col & 7))];
            bx.v = bframe[col * 64 + (u ^ (col & 7))];
            A.w[0] = ax.w[0]; A.w[1] = ax.w[1]; A.w[2] = ax.w[2]; A.w[3] = ax.w[3];
            B.w[0] = bx.w[0]; B.w[1] = bx.w[1]; B.w[2] = bx.w[2]; B.w[3] = bx.w[3];
            acc = __builtin_amdgcn_mfma_f32_16x16x32_f16(A.v, B.v, acc, 0, 0, 0);
        }

        // ---- theta, argmin, epilogue: 4 chains per lane ----
        float c1r[4], c2r[4], o0r[4];
        int bir[4];
#pragma unroll
        for (int r4 = 0; r4 < 4; ++r4) {
            const float th = fmaxf(fmaf(x0r[r4], af0c, -acc[r4]), thmin);
            FU u; u.f = th;
            u32 key = (u.u & 0xFFFFFFF0u) | (u32)col;
#pragma unroll
            for (int m = 1; m <= 8; m <<= 1) {
                const u32 o = (u32)__shfl_xor((int)key, m);
                key = o < key ? o : key;
            }
            const int bi  = (int)(key & 15u);
            const int src = (lane & 48) | bi;
            const float thw = __shfl(th, src);     // exact winner theta
            const float y0  = __shfl(af0c, src);   // winner af0

            const float s2 = thw * thw - 1.0f;
            const float rr = sqrtf(s2);
            const float ac = __logf(thw + rr);     // arccosh
            const float cf = ac / rr;
            const float vn = sqrtf(fmaxf(ALPHA * ALPHA * ac * ac, EPSV));
            const float e  = __expf(vn);
            const float ei = 1.0f / e;
            const float ch = 0.5f * (e + ei);
            const float sh = 0.5f * (e - ei);
            const float c2 = ALPHA * cf * (sh / vn);
            const float c1 = fmaf(-c2, thw, ch);

            c1r[r4] = c1;
            c2r[r4] = c2;
            o0r[r4] = fmaf(c2, y0, c1 * x0r[r4]);
            bir[r4] = bi;
        }

        // ---- store: 8 rows, two contiguous dwordx4 streams per row ----
#pragma unroll
        for (int r = 0; r < 8; ++r) {
            const int src = (r >> 2) * 16;        // producer lane-group
            const float c1 = __shfl(c1r[r & 3], src);
            const float c2 = __shfl(c2r[r & 3], src);
            const float o0 = __shfl(o0r[r & 3], src);
            const int   bi = __builtin_amdgcn_readfirstlane(__shfl(bir[r & 3], src));

            U4 X, Y;
            X.v = xf[r * 64 + (lane ^ (r & 7))];
            Y.v = bframe[bi * 64 + (lane ^ (bi & 7))];

            f32x4u s0, s1;
#pragma unroll
            for (int q = 0; q < 2; ++q) {
                const h2v hx = asH2(X.w[q]);
                const h2v hy = asH2(Y.w[q]);
                s0[2 * q]     = fmaf(c2, (float)hy.x, c1 * (float)hx.x);
                s0[2 * q + 1] = fmaf(c2, (float)hy.y, c1 * (float)hx.y);
            }
#pragma unroll
            for (int q = 0; q < 2; ++q) {
                const h2v hx = asH2(X.w[2 + q]);
                const h2v hy = asH2(Y.w[2 + q]);
                s1[2 * q]     = fmaf(c2, (float)hy.x, c1 * (float)hx.x);
                s1[2 * q + 1] = fmaf(c2, (float)hy.y, c1 * (float)hx.y);
            }
            float* op = out + (size_t)(rowbase + r) * DD;
            __builtin_nontemporal_store(s0, (f32x4u*)(op + 1 + 4 * lane));
            __builtin_nontemporal_store(s1, (f32x4u*)(op + 257 + 4 * lane));
            if (lane == 0) __builtin_nontemporal_store(o0, op);
        }
    }
}

extern "C" void kernel_launch(void* const* d_in, const int* in_sizes, int n_in,
                              void* d_out, int out_size, void* d_ws, size_t ws_size,
                              hipStream_t stream) {
    const float* x   = (const float*)d_in[0];
    const float* anc = (const float*)d_in[1];
    float* out       = (float*)d_out;
    hipLaunchKernelGGL(hfield_kernel, dim3(GRID), dim3(256), 0, stream, x, anc, out);
}